// Round 7
// baseline (289.937 us; speedup 1.0000x reference)
//
#include <hip/hip_runtime.h>
#include <hip/hip_bf16.h>
#include <hip/hip_fp16.h>
#include <math.h>

#define NB 64
#define CC 512
#define LL 256

typedef __attribute__((ext_vector_type(4))) float floatx4;
typedef __attribute__((ext_vector_type(8))) short short8;

static __device__ __forceinline__ unsigned f2bf2(float x, float y) {
    __hip_bfloat162 h = __float22bfloat162_rn(make_float2(x, y));
    union { __hip_bfloat162 h; unsigned u; } c; c.h = h;
    return c.u;   // low 16 = x, high 16 = y
}
static __device__ __forceinline__ unsigned f2h(float x) {
    __half h = __float2half_rn(x);
    union { __half h; unsigned short u; } c; c.h = h;
    return (unsigned)c.u;
}
static __device__ __forceinline__ float h2f(unsigned u) {
    union { unsigned short u; __half h; } c; c.u = (unsigned short)u;
    return __half2float(c.h);
}

__global__ void zero_kernel(float* sumS, float* sumT, int* cnt, float* out) {
    const int t = threadIdx.x;
    if (t < NB) { sumS[t] = 0.0f; sumT[t] = 0.0f; }
    cnt[t] = 0;                       // 64*16 ints, block is 1024 threads
    if (t == 0) out[0] = 0.0f;
}

// Single fused kernel. Per (batch, upper-tri 64x64 tile): ballot-compact, stage bf16
// rows to LDS with register prefetch (row norms inline), dual MFMA Gram, distances
// kept packed fp16 in registers, per-batch sum atomics + arrival counter, spin until
// the batch's 36 blocks arrive, then Huber from registers.
__global__ __launch_bounds__(256) void fused_kernel(
    const float* __restrict__ S, const float* __restrict__ T,
    const int* __restrict__ targets,
    float* __restrict__ sumS, float* __restrict__ sumT,
    int* __restrict__ cnt, float* __restrict__ out)
{
    const int bx = blockIdx.x;
    const int n = bx / 36, lin = bx - n * 36;
    int tI = 0, rem = lin;                    // linear -> upper-tri (tI,tJ) of 8x8
    while (rem >= 8 - tI) { rem -= 8 - tI; ++tI; }
    const int tJ = tI + rem;
    const bool diag = (tI == tJ);

    __shared__ int s_idx[CC];
    __shared__ int s_cnt[8], s_off[8];
    __shared__ int s_npS;
    __shared__ __align__(16) unsigned short lds[4][64][40];   // 20480 B
    __shared__ float s_norm[4][64];
    __shared__ float redA[4], redB[4];
    __shared__ float s_inv[2];

    const int tid = threadIdx.x;
    const int w = tid >> 6, lane = tid & 63;

    // ---- deterministic ballot compaction (ascending index order) ----
    const int* tg = targets + n * CC;
    const bool p0 = tg[tid] != 0;
    const bool p1 = tg[tid + 256] != 0;
    const unsigned long long m0 = __ballot(p0);
    const unsigned long long m1 = __ballot(p1);
    if (lane == 0) { s_cnt[w] = __popcll(m0); s_cnt[4 + w] = __popcll(m1); }
    __syncthreads();
    if (tid == 0) {
        int a = 0;
        for (int i = 0; i < 8; ++i) { s_off[i] = a; a += s_cnt[i]; }
        s_npS = a;
    }
    __syncthreads();
    const unsigned long long below = (1ull << lane) - 1ull;
    if (p0) s_idx[s_off[w] + __popcll(m0 & below)] = tid;
    if (p1) s_idx[s_off[4 + w] + __popcll(m1 & below)] = tid + 256;
    __syncthreads();
    const int np = s_npS;

    const bool work = (np >= 2) && (tI * 64 < np) && (tJ * 64 < np);

    const int m16 = lane & 15, quad = lane >> 4;
    const int bufB = diag ? 0 : 1;
    const int wrow = w * 16;
    unsigned dpk[16];                         // (fp16 ds | fp16 dt<<16) per pair
    float t0 = 0.0f, t1 = 0.0f;

    if (work) {
        // wave w stages buffer w: 0=S-A, 1=S-B, 2=T-A, 3=T-B (diag: B aliases A)
        const bool stager = (!diag) || ((w & 1) == 0);
        const char* Pbase = (const char*)(((w >> 1) ? T : S) + (size_t)n * CC * LL);
        const int tileBase = ((w & 1) ? tJ : tI) * 64;
        const int r8 = lane >> 3, c8 = lane & 7;   // 8 lanes/row, 128 B per row-chunk
        unsigned off_[8];
        #pragma unroll
        for (int i = 0; i < 8; ++i) {
            const int gk = tileBase + r8 + 8 * i;
            const int row = s_idx[(gk < np) ? gk : 0];
            off_[i] = (unsigned)(row * LL * 4 + c8 * 16);
        }

        float4 pre[8];
        float nprt[8];
        #pragma unroll
        for (int i = 0; i < 8; ++i) nprt[i] = 0.0f;
        if (stager) {
            #pragma unroll
            for (int i = 0; i < 8; ++i) pre[i] = *(const float4*)(Pbase + off_[i]);
        }

        floatx4 accS[4], accT[4];
        #pragma unroll
        for (int c = 0; c < 4; ++c) {
            accS[c][0] = 0; accS[c][1] = 0; accS[c][2] = 0; accS[c][3] = 0;
            accT[c][0] = 0; accT[c][1] = 0; accT[c][2] = 0; accT[c][3] = 0;
        }

        for (int kk = 0; kk < 8; ++kk) {
            __syncthreads();   // prior chunk's LDS reads complete
            if (stager) {
                #pragma unroll
                for (int i = 0; i < 8; ++i) {
                    nprt[i] += pre[i].x * pre[i].x + pre[i].y * pre[i].y +
                               pre[i].z * pre[i].z + pre[i].w * pre[i].w;
                    *(uint2*)&lds[w][r8 + 8 * i][c8 * 4] =
                        make_uint2(f2bf2(pre[i].x, pre[i].y), f2bf2(pre[i].z, pre[i].w));
                }
            }
            __syncthreads();
            if (stager && kk < 7) {            // prefetch next chunk during MFMA
                #pragma unroll
                for (int i = 0; i < 8; ++i)
                    pre[i] = *(const float4*)(Pbase + off_[i] + (kk + 1) * 128);
            }
            const int aoff = (wrow + m16) * 40 + quad * 8;
            const short8 a_s = *(const short8*)(&lds[0][0][0] + aoff);
            const short8 a_t = *(const short8*)(&lds[2][0][0] + aoff);
            #pragma unroll
            for (int c = 0; c < 4; ++c) {
                const int boff = (c * 16 + m16) * 40 + quad * 8;
                const short8 b_s = *(const short8*)(&lds[bufB][0][0] + boff);
                const short8 b_t = *(const short8*)(&lds[2 + bufB][0][0] + boff);
                accS[c] = __builtin_amdgcn_mfma_f32_16x16x32_bf16(a_s, b_s, accS[c], 0, 0, 0);
                accT[c] = __builtin_amdgcn_mfma_f32_16x16x32_bf16(a_t, b_t, accT[c], 0, 0, 0);
            }
        }

        // ---- inline norms: reduce the 8 lanes (c8) sharing each staged row ----
        if (stager) {
            #pragma unroll
            for (int i = 0; i < 8; ++i) {
                float v = nprt[i];
                v += __shfl_xor(v, 1); v += __shfl_xor(v, 2); v += __shfl_xor(v, 4);
                if (c8 == 0) s_norm[w][r8 + 8 * i] = v;
            }
        }
        __syncthreads();

        // ---- distances; C/D layout: col=lane&15, row=quad*4+reg ----
        float l0 = 0.0f, l1 = 0.0f;
        #pragma unroll
        for (int c = 0; c < 4; ++c) {
            const int colL = c * 16 + m16;
            const int gj = tJ * 64 + colL;
            const float nBs = s_norm[bufB][colL];
            const float nBt = s_norm[2 + bufB][colL];
            #pragma unroll
            for (int r = 0; r < 4; ++r) {
                const int rowL = wrow + quad * 4 + r;
                const int gi = tI * 64 + rowL;
                const float ds = sqrtf(fmaxf(s_norm[0][rowL] + nBs - 2.0f * accS[c][r], 1e-12f));
                const float dt = sqrtf(fmaxf(s_norm[2][rowL] + nBt - 2.0f * accT[c][r], 1e-12f));
                if (gi < np && gj < np && gi != gj) { l0 += ds; l1 += dt; }
                dpk[c * 4 + r] = f2h(ds) | (f2h(dt) << 16);
            }
        }

        #pragma unroll
        for (int o = 32; o; o >>= 1) { l0 += __shfl_down(l0, o); l1 += __shfl_down(l1, o); }
        if (lane == 0) { redA[w] = l0; redB[w] = l1; }
        __syncthreads();
        if (tid == 0) {
            const float wgt = diag ? 1.0f : 2.0f;   // off-diag tiles mirror-counted
            t0 = wgt * (redA[0] + redA[1] + redA[2] + redA[3]);
            t1 = wgt * (redB[0] + redB[1] + redB[2] + redB[3]);
        }
    }

    // ---- per-batch arrival + spin (tid 0 only), then broadcast normalizers ----
    if (tid == 0) {
        if (work) {
            if (t0 != 0.0f) atomicAdd(&sumS[n], t0);
            if (t1 != 0.0f) atomicAdd(&sumT[n], t1);
        }
        __threadfence();
        __hip_atomic_fetch_add(&cnt[n * 16], 1, __ATOMIC_ACQ_REL, __HIP_MEMORY_SCOPE_AGENT);
        if (work) {
            while (__hip_atomic_load(&cnt[n * 16], __ATOMIC_ACQUIRE,
                                     __HIP_MEMORY_SCOPE_AGENT) < 36)
                __builtin_amdgcn_s_sleep(8);
            const float ss = __hip_atomic_load(&sumS[n], __ATOMIC_RELAXED,
                                               __HIP_MEMORY_SCOPE_AGENT);
            const float st = __hip_atomic_load(&sumT[n], __ATOMIC_RELAXED,
                                               __HIP_MEMORY_SCOPE_AGENT);
            const float cp = (float)np * (float)(np - 1);
            s_inv[0] = cp / ss;
            s_inv[1] = cp / st;
        }
    }
    if (!work) return;                         // block-uniform: safe vs barrier below
    __syncthreads();

    // ---- Huber from registers ----
    const float inv_ms = s_inv[0], inv_mt = s_inv[1];
    float h = 0.0f;
    #pragma unroll
    for (int c = 0; c < 4; ++c) {
        const int gj = tJ * 64 + c * 16 + m16;
        #pragma unroll
        for (int r = 0; r < 4; ++r) {
            const int gi = tI * 64 + wrow + quad * 4 + r;
            if (gi < np && gj < np && gi != gj) {
                const unsigned u = dpk[c * 4 + r];
                const float ds = h2f(u & 0xffffu);
                const float dt = h2f(u >> 16);
                const float diff = ds * inv_ms - dt * inv_mt;
                const float ad = fabsf(diff);
                h += (ad < 1.0f) ? 0.5f * diff * diff : ad - 0.5f;
            }
        }
    }
    #pragma unroll
    for (int o = 32; o; o >>= 1) h += __shfl_down(h, o);
    if (lane == 0) redA[w] = h;
    __syncthreads();
    if (tid == 0)
        atomicAdd(out, (diag ? 1.0f : 2.0f) * (redA[0] + redA[1] + redA[2] + redA[3]) / (float)np);
}

extern "C" void kernel_launch(void* const* d_in, const int* in_sizes, int n_in,
                              void* d_out, int out_size, void* d_ws, size_t ws_size,
                              hipStream_t stream) {
    const float* S = (const float*)d_in[0];
    const float* T = (const float*)d_in[1];
    const int* targets = (const int*)d_in[2];
    float* out = (float*)d_out;

    float* sumS = (float*)d_ws;              // 64
    float* sumT = sumS + NB;                 // 64
    int* cnt = (int*)(sumT + NB);            // 64*16 (64B-spaced counters)

    zero_kernel<<<1, 1024, 0, stream>>>(sumS, sumT, cnt, out);
    fused_kernel<<<NB * 36, 256, 0, stream>>>(S, T, targets, sumS, sumT, cnt, out);
}

// Round 8
// 133.260 us; speedup vs baseline: 2.1757x; 2.1757x over previous
//
#include <hip/hip_runtime.h>
#include <hip/hip_bf16.h>
#include <hip/hip_fp16.h>
#include <math.h>

#define NB 64
#define CC 512
#define LL 256

typedef __attribute__((ext_vector_type(4))) float floatx4;
typedef __attribute__((ext_vector_type(8))) short short8;

static __device__ __forceinline__ unsigned f2bf2(float x, float y) {
    __hip_bfloat162 h = __float22bfloat162_rn(make_float2(x, y));
    union { __hip_bfloat162 h; unsigned u; } c; c.h = h;
    return c.u;   // low 16 = x, high 16 = y
}
static __device__ __forceinline__ unsigned f2h(float x) {
    __half h = __float2half_rn(x);
    union { __half h; unsigned short u; } c; c.h = h;
    return (unsigned)c.u;
}
static __device__ __forceinline__ float h2f(unsigned u) {
    union { unsigned short u; __half h; } c; c.u = (unsigned short)u;
    return __half2float(c.h);
}

// ---------------- Kernel 1: fused compact + inline norms + dual Gram + distances ----
// 1-D grid, bx = lin*64 + n  =>  bx % 8 == n % 8: all 36 tile-blocks of batch n land
// on the same XCD (round-robin dispatch), so the batch's 0.5 MB row data stays in
// that XCD's L2 across all its tiles.
__global__ __launch_bounds__(256) void dist_kernel(
    const float* __restrict__ S, const float* __restrict__ T,
    const int* __restrict__ targets,
    float* __restrict__ psumS, float* __restrict__ psumT,
    int* __restrict__ npos_ws, unsigned* __restrict__ D,
    float* __restrict__ out)
{
    const int bx = blockIdx.x;
    const int n = bx & (NB - 1), lin = bx >> 6;
    int tI = 0, rem = lin;                    // linear -> upper-tri (tI,tJ) of 8x8
    while (rem >= 8 - tI) { rem -= 8 - tI; ++tI; }
    const int tJ = tI + rem;
    const bool diag = (tI == tJ);

    __shared__ int s_idx[CC];
    __shared__ int s_cnt[8], s_off[8];
    __shared__ int s_npS;
    __shared__ __align__(16) unsigned short lds[4][64][40];   // 20480 B
    __shared__ float s_norm[4][64];
    __shared__ float redA[4], redB[4];

    const int tid = threadIdx.x;
    const int w = tid >> 6, lane = tid & 63;

    // ---- deterministic ballot compaction (ascending index order) ----
    const int* tg = targets + n * CC;
    const bool p0 = tg[tid] != 0;
    const bool p1 = tg[tid + 256] != 0;
    const unsigned long long m0 = __ballot(p0);
    const unsigned long long m1 = __ballot(p1);
    if (lane == 0) { s_cnt[w] = __popcll(m0); s_cnt[4 + w] = __popcll(m1); }
    __syncthreads();
    if (tid == 0) {
        int a = 0;
        for (int i = 0; i < 8; ++i) { s_off[i] = a; a += s_cnt[i]; }
        s_npS = a;
    }
    __syncthreads();
    const unsigned long long below = (1ull << lane) - 1ull;
    if (p0) s_idx[s_off[w] + __popcll(m0 & below)] = tid;
    if (p1) s_idx[s_off[4 + w] + __popcll(m1 & below)] = tid + 256;
    __syncthreads();
    const int np = s_npS;

    if (tid == 0 && lin == 0) {
        npos_ws[n] = np;
        if (n == 0) out[0] = 0.0f;            // K2 strictly follows K1: safe
    }

    const bool work = (np >= 2) && (tI * 64 < np) && (tJ * 64 < np);

    float t0 = 0.0f, t1 = 0.0f;
    if (work) {
        // wave w stages buffer w: 0=S-A, 1=S-B, 2=T-A, 3=T-B (diag: B aliases A)
        const bool stager = (!diag) || ((w & 1) == 0);
        const char* Pbase = (const char*)(((w >> 1) ? T : S) + (size_t)n * CC * LL);
        const int tileBase = ((w & 1) ? tJ : tI) * 64;
        const int r8 = lane >> 3, c8 = lane & 7;   // 8 lanes/row, 128 B per row-chunk
        unsigned off_[8];
        #pragma unroll
        for (int i = 0; i < 8; ++i) {
            const int gk = tileBase + r8 + 8 * i;
            const int row = s_idx[(gk < np) ? gk : 0];
            off_[i] = (unsigned)(row * LL * 4 + c8 * 16);
        }

        float4 pre[8];
        float nprt[8];
        #pragma unroll
        for (int i = 0; i < 8; ++i) nprt[i] = 0.0f;
        if (stager) {
            #pragma unroll
            for (int i = 0; i < 8; ++i) pre[i] = *(const float4*)(Pbase + off_[i]);
        }

        const int m16 = lane & 15, quad = lane >> 4;
        const int bufB = diag ? 0 : 1;
        const int wrow = w * 16;

        floatx4 accS[4], accT[4];
        #pragma unroll
        for (int c = 0; c < 4; ++c) {
            accS[c][0] = 0; accS[c][1] = 0; accS[c][2] = 0; accS[c][3] = 0;
            accT[c][0] = 0; accT[c][1] = 0; accT[c][2] = 0; accT[c][3] = 0;
        }

        for (int kk = 0; kk < 8; ++kk) {
            __syncthreads();   // prior chunk's LDS reads complete
            if (stager) {
                #pragma unroll
                for (int i = 0; i < 8; ++i) {
                    nprt[i] += pre[i].x * pre[i].x + pre[i].y * pre[i].y +
                               pre[i].z * pre[i].z + pre[i].w * pre[i].w;
                    *(uint2*)&lds[w][r8 + 8 * i][c8 * 4] =
                        make_uint2(f2bf2(pre[i].x, pre[i].y), f2bf2(pre[i].z, pre[i].w));
                }
            }
            __syncthreads();
            if (stager && kk < 7) {            // prefetch next chunk during MFMA
                #pragma unroll
                for (int i = 0; i < 8; ++i)
                    pre[i] = *(const float4*)(Pbase + off_[i] + (kk + 1) * 128);
            }
            const int aoff = (wrow + m16) * 40 + quad * 8;
            const short8 a_s = *(const short8*)(&lds[0][0][0] + aoff);
            const short8 a_t = *(const short8*)(&lds[2][0][0] + aoff);
            #pragma unroll
            for (int c = 0; c < 4; ++c) {
                const int boff = (c * 16 + m16) * 40 + quad * 8;
                const short8 b_s = *(const short8*)(&lds[bufB][0][0] + boff);
                const short8 b_t = *(const short8*)(&lds[2 + bufB][0][0] + boff);
                accS[c] = __builtin_amdgcn_mfma_f32_16x16x32_bf16(a_s, b_s, accS[c], 0, 0, 0);
                accT[c] = __builtin_amdgcn_mfma_f32_16x16x32_bf16(a_t, b_t, accT[c], 0, 0, 0);
            }
        }

        // ---- inline norms: reduce the 8 lanes (c8) sharing each staged row ----
        if (stager) {
            #pragma unroll
            for (int i = 0; i < 8; ++i) {
                float v = nprt[i];
                v += __shfl_xor(v, 1); v += __shfl_xor(v, 2); v += __shfl_xor(v, 4);
                if (c8 == 0) s_norm[w][r8 + 8 * i] = v;
            }
        }
        __syncthreads();

        // ---- distances; C/D layout: col=lane&15, row=quad*4+reg ----
        unsigned* Dn = D + ((size_t)bx << 12);   // 64x64 entries
        float l0 = 0.0f, l1 = 0.0f;
        #pragma unroll
        for (int c = 0; c < 4; ++c) {
            const int colL = c * 16 + m16;
            const int gj = tJ * 64 + colL;
            const float nBs = s_norm[bufB][colL];
            const float nBt = s_norm[2 + bufB][colL];
            #pragma unroll
            for (int r = 0; r < 4; ++r) {
                const int rowL = wrow + quad * 4 + r;
                const int gi = tI * 64 + rowL;
                const float ds = sqrtf(fmaxf(s_norm[0][rowL] + nBs - 2.0f * accS[c][r], 1e-12f));
                const float dt = sqrtf(fmaxf(s_norm[2][rowL] + nBt - 2.0f * accT[c][r], 1e-12f));
                if (gi < np && gj < np && gi != gj) { l0 += ds; l1 += dt; }
                Dn[rowL * 64 + colL] = f2h(ds) | (f2h(dt) << 16);
            }
        }

        #pragma unroll
        for (int o = 32; o; o >>= 1) { l0 += __shfl_down(l0, o); l1 += __shfl_down(l1, o); }
        if (lane == 0) { redA[w] = l0; redB[w] = l1; }
        __syncthreads();
        if (tid == 0) {
            const float wgt = diag ? 1.0f : 2.0f;   // off-diag tiles mirror-counted
            t0 = wgt * (redA[0] + redA[1] + redA[2] + redA[3]);
            t1 = wgt * (redB[0] + redB[1] + redB[2] + redB[3]);
        }
    }
    if (tid == 0) { psumS[bx] = t0; psumT[bx] = t1; }
}

// ---------------- Kernel 2: streaming Huber over packed (ds, dt) ----------------
// Same bx mapping as K1 so each block reads the D tile its XCD just wrote (L2-hot).
__global__ __launch_bounds__(256) void huber_kernel(
    const unsigned* __restrict__ D, const int* __restrict__ npos,
    const float* __restrict__ psumS, const float* __restrict__ psumT,
    float* __restrict__ out)
{
    const int bx = blockIdx.x;
    const int n = bx & (NB - 1), lin = bx >> 6;
    int tI = 0, rem = lin;
    while (rem >= 8 - tI) { rem -= 8 - tI; ++tI; }
    const int tJ = tI + rem;

    const int np = npos[n];
    if (np < 2) return;
    if (tI * 64 >= np || tJ * 64 >= np) return;

    float ss = 0.0f, st = 0.0f;
    #pragma unroll
    for (int t = 0; t < 36; ++t) { ss += psumS[t * 64 + n]; st += psumT[t * 64 + n]; }
    const float cnt = (float)np * (float)(np - 1);
    const float inv_ms = cnt / ss;
    const float inv_mt = cnt / st;

    const uint4* Dn = (const uint4*)(D + ((size_t)bx << 12));
    const int tid = threadIdx.x;

    float h = 0.0f;
    #pragma unroll
    for (int it = 0; it < 4; ++it) {
        const int e4 = it * 256 + tid;        // uint4 index; element = e4*4
        const uint4 v = Dn[e4];
        const unsigned vv[4] = { v.x, v.y, v.z, v.w };
        const int e0 = e4 * 4;
        #pragma unroll
        for (int k = 0; k < 4; ++k) {
            const int e = e0 + k;
            const int gi = tI * 64 + (e >> 6);
            const int gj = tJ * 64 + (e & 63);
            if (gi < np && gj < np && gi != gj) {
                const float ds = h2f(vv[k] & 0xffffu);
                const float dt = h2f(vv[k] >> 16);
                const float diff = ds * inv_ms - dt * inv_mt;
                const float ad = fabsf(diff);
                h += (ad < 1.0f) ? 0.5f * diff * diff : ad - 0.5f;
            }
        }
    }

    #pragma unroll
    for (int o = 32; o; o >>= 1) h += __shfl_down(h, o);
    __shared__ float red[4];
    const int w = tid >> 6, lane = tid & 63;
    if (lane == 0) red[w] = h;
    __syncthreads();
    if (tid == 0) {
        const float wgt = (tI == tJ) ? 1.0f : 2.0f;
        atomicAdd(out, wgt * (red[0] + red[1] + red[2] + red[3]) / (float)np);
    }
}

extern "C" void kernel_launch(void* const* d_in, const int* in_sizes, int n_in,
                              void* d_out, int out_size, void* d_ws, size_t ws_size,
                              hipStream_t stream) {
    const float* S = (const float*)d_in[0];
    const float* T = (const float*)d_in[1];
    const int* targets = (const int*)d_in[2];
    float* out = (float*)d_out;

    float* psumS = (float*)d_ws;             // 2304
    float* psumT = psumS + 2304;             // 2304
    int* npos_ws = (int*)(psumT + 2304);     // 64
    size_t off = ((size_t)((char*)(npos_ws + 64) - (char*)d_ws) + 255) & ~(size_t)255;
    unsigned* D = (unsigned*)((char*)d_ws + off);   // 2304 * 4096 uint = 37.7 MB

    dist_kernel<<<NB * 36, 256, 0, stream>>>(S, T, targets, psumS, psumT, npos_ws, D, out);
    huber_kernel<<<NB * 36, 256, 0, stream>>>(D, npos_ws, psumS, psumT, out);
}